// Round 11
// baseline (167.912 us; speedup 1.0000x reference)
//
#include <hip/hip_runtime.h>
#include <stdint.h>

typedef unsigned short u16;
typedef unsigned int u32;
typedef __attribute__((ext_vector_type(4))) float f32x4;
typedef __attribute__((ext_vector_type(4))) unsigned int u32x4;
typedef __attribute__((ext_vector_type(4))) unsigned short u16x4;
typedef __attribute__((ext_vector_type(8))) __bf16 bf16x8;

union Frag { u32x4 u; bf16x8 b; };

__device__ __forceinline__ u16 f2bf(float x) {
  u32 u = __float_as_uint(x);
  u32 r = (u + 0x7fffu + ((u >> 16) & 1u)) >> 16;
  return (u16)r;
}
__device__ __forceinline__ float bf2f(u16 v) {
  u32 u = ((u32)v) << 16;
  return __uint_as_float(u);
}
__device__ __forceinline__ float sigmoidf_(float x) { return 1.0f / (1.0f + __expf(-x)); }

// async global->LDS, 16B per lane; LDS dest = wave-uniform base + lane*16
__device__ __forceinline__ void gload16(const void* g, void* lds) {
  __builtin_amdgcn_global_load_lds((const __attribute__((address_space(1))) unsigned int*)g,
                                   (__attribute__((address_space(3))) unsigned int*)lds, 16, 0, 0);
}

// ---------------------------------------------------------------------------
// MFMA GEMM body, BMxBN tile (BM = 32*MI, BN = 32*NI), BK=64, 256 threads
// (4 waves as 2x2). Double-buffered LDS (T3 minimum-2-phase): STAGE(t+1)
// issued BEFORE compute(t); ONE barrier per K-step. Requires K % 128 == 0.
// NOTE (R6 lesson): persistent-kernel software grid barriers cost ~25us each
// on 8-XCD MI355X (L2 writeback+inv per fence) — kernel relaunch is cheaper.
// NOTE (R7/R8 lesson): 1 block/CU exposes barrier drains; size grids >= 512.
// NOTE (R9/R10 lesson): biasz co-scheduling and XCD swizzle are NEUTRAL —
// L3 absorbs cross-XCD refetch; launch partitioning is not the limiter.
// EPI: 0 = f32 (+bias), 1 = bf16, 2 = f32 x1 = e0 + v*sigmoid(e1) [per-elem],
//      3 = f32 out = e0 + v*e1[row]
//      4 = bf16 swiglu over interleaved 16-col pairs, width N/2   [NI4 only]
//      5 = bf16 adaln over interleaved pairs, width N/2 (e0=x,e1=xstat) [NI4]
//      6 = bf16 out, V columns (2048..3071) transposed to vT      [NI4 only]
//          (vT pointer smuggled via `bias`)
// ---------------------------------------------------------------------------
template<int EPI, int MI, int NI>
__device__ __forceinline__ void gemm_body(int bx, int by,
                                          u16* As0, u16* As1, u16* Bs0, u16* Bs1,
                                          const u16* __restrict__ A, const u16* __restrict__ Bt,
                                          const float* __restrict__ bias,
                                          const float* __restrict__ e0, const float* __restrict__ e1,
                                          void* __restrict__ Cp, int M, int N, int K) {
  constexpr int BM = 32 * MI;
  constexpr int BN = 32 * NI;
  const int t = threadIdx.x, wave = t >> 6, lane = t & 63;
  const int lrow = lane & 15, lgrp = lane >> 4;
  const int m0 = bx * BM, n0 = by * BN;
  const int wr = (wave >> 1) * (16 * MI), wc = (wave & 1) * (16 * NI);

  const int srow = wave * 8 + (lane >> 3);
  const int scol = (((lane & 7) ^ (lane >> 3)) << 3);
  const u16* Ab = A + (size_t)(m0 + srow) * K + scol;
  const u16* Bb = Bt + (size_t)(n0 + srow) * K + scol;

  f32x4 acc[MI][NI] = {};

  auto stage = [&](int k0, u16* Asd, u16* Bsd) {
#pragma unroll
    for (int i = 0; i < MI; ++i) gload16(Ab + (size_t)i * 32 * K + k0, Asd + wave * 512 + i * 2048);
#pragma unroll
    for (int i = 0; i < NI; ++i) gload16(Bb + (size_t)i * 32 * K + k0, Bsd + wave * 512 + i * 2048);
  };
  auto compute = [&](const u16* Asr, const u16* Bsr) {
#pragma unroll
    for (int ks = 0; ks < 2; ++ks) {
      Frag af[MI], bf4[NI];
#pragma unroll
      for (int mi = 0; mi < MI; ++mi) {
        int row = wr + mi * 16 + lrow;
        int slot = ((ks << 2) + lgrp) ^ (row & 7);
        af[mi].u = *(const u32x4*)((const char*)Asr + row * 128 + (slot << 4));
      }
#pragma unroll
      for (int ni = 0; ni < NI; ++ni) {
        int row = wc + ni * 16 + lrow;
        int slot = ((ks << 2) + lgrp) ^ (row & 7);
        bf4[ni].u = *(const u32x4*)((const char*)Bsr + row * 128 + (slot << 4));
      }
#pragma unroll
      for (int mi = 0; mi < MI; ++mi)
#pragma unroll
        for (int ni = 0; ni < NI; ++ni)
          acc[mi][ni] = __builtin_amdgcn_mfma_f32_16x16x32_bf16(af[mi].b, bf4[ni].b, acc[mi][ni], 0, 0, 0);
    }
  };

  stage(0, As0, Bs0);
  __syncthreads();
  for (int k0 = 0; k0 < K; k0 += 128) {
    stage(k0 + 64, As1, Bs1);
    compute(As0, Bs0);
    __syncthreads();
    if (k0 + 128 < K) stage(k0 + 128, As0, Bs0);
    compute(As1, Bs1);
    __syncthreads();
  }

  if constexpr (EPI == 4 || EPI == 5) {
    const int half = N >> 1;
#pragma unroll
    for (int mi = 0; mi < MI; ++mi) {
#pragma unroll
      for (int np = 0; np < 2; ++np) {
        int j = ((n0 + wc) >> 1) + np * 16 + lrow;
        float bj = 0.0f;
        if (EPI == 5) bj = bias[j];
#pragma unroll
        for (int rg = 0; rg < 4; ++rg) {
          int row = m0 + wr + mi * 16 + lgrp * 4 + rg;
          float a = acc[mi][2 * np][rg];
          float b = acc[mi][2 * np + 1][rg];
          float val;
          if constexpr (EPI == 4) {
            val = a * sigmoidf_(a) * b;
          } else {
            float mean = e1[2 * row], rinv = e1[2 * row + 1];
            float lnx = (e0[(size_t)row * half + j] - mean) * rinv;
            val = lnx * sigmoidf_(a + bj) + b;
          }
          ((u16*)Cp)[(size_t)row * half + j] = f2bf(val);
        }
      }
    }
  } else if constexpr (EPI == 6) {
    u16* vTp = (u16*)bias;  // smuggled vT pointer
    const bool isv = (n0 >= 2048) && (n0 < 3072);
#pragma unroll
    for (int mi = 0; mi < MI; ++mi) {
#pragma unroll
      for (int ni = 0; ni < NI; ++ni) {
        int col = n0 + wc + ni * 16 + lrow;
        int rowb = m0 + wr + mi * 16 + lgrp * 4;
        if (isv) {
          int h = (col - 2048) >> 6, d = col & 63;
          int b = rowb >> 9, n = rowb & 511;
          u16x4 o;
#pragma unroll
          for (int rg = 0; rg < 4; ++rg) o[rg] = f2bf(acc[mi][ni][rg]);
          *(u16x4*)(vTp + ((size_t)((b * 16 + h) * 64 + d)) * 512 + n) = o;
        } else {
#pragma unroll
          for (int rg = 0; rg < 4; ++rg)
            ((u16*)Cp)[(size_t)(rowb + rg) * N + col] = f2bf(acc[mi][ni][rg]);
        }
      }
    }
  } else {
#pragma unroll
    for (int mi = 0; mi < MI; ++mi) {
#pragma unroll
      for (int ni = 0; ni < NI; ++ni) {
        int col = n0 + wc + ni * 16 + lrow;
        float bv = 0.0f;
        if (EPI == 0 && bias) bv = bias[col];
#pragma unroll
        for (int rg = 0; rg < 4; ++rg) {
          int row = m0 + wr + mi * 16 + lgrp * 4 + rg;
          size_t idx = (size_t)row * N + col;
          float v = acc[mi][ni][rg];
          if constexpr (EPI == 0)      ((float*)Cp)[idx] = v + bv;
          else if constexpr (EPI == 1) ((u16*)Cp)[idx] = f2bf(v);
          else if constexpr (EPI == 2) ((float*)Cp)[idx] = e0[idx] + v * sigmoidf_(e1[idx]);
          else                         ((float*)Cp)[idx] = e0[idx] + v * e1[row];
        }
      }
    }
  }
  (void)M;
}

template<int EPI, int MI, int NI>
__global__ __launch_bounds__(256) void gemm_t(const u16* __restrict__ A, const u16* __restrict__ Bt,
                                              const float* __restrict__ bias,
                                              const float* __restrict__ e0, const float* __restrict__ e1,
                                              void* __restrict__ Cp, int M, int N, int K) {
  __shared__ u16 As0[32 * MI * 64], As1[32 * MI * 64];
  __shared__ u16 Bs0[32 * NI * 64], Bs1[32 * NI * 64];
  gemm_body<EPI, MI, NI>(blockIdx.x, blockIdx.y, As0, As1, Bs0, Bs1, A, Bt, bias, e0, e1, Cp, M, N, K);
}

// ---------------------------------------------------------------------------
// Fused adaln-gemm (EPI5,MI2,NI4; 256 blocks) + cond-gate gemm (EPI0,MI1,NI2;
// 512 blocks) -> 768 blocks = 3/CU mix
// ---------------------------------------------------------------------------
__global__ __launch_bounds__(256) void gemm_adaln_cg(
    const u16* __restrict__ cnb, const u16* __restrict__ gbT, const float* __restrict__ gamma_b,
    const float* __restrict__ x, const float* __restrict__ xstat, u16* __restrict__ xbf,
    const u16* __restrict__ cb, const u16* __restrict__ cgT, const float* __restrict__ b_cg,
    float* __restrict__ cglin) {
  __shared__ u16 As0[64 * 64], As1[64 * 64];
  __shared__ u16 Bs0[128 * 64], Bs1[128 * 64];
  int id = blockIdx.x;
  if (id < 256) {
    gemm_body<5, 2, 4>(id & 15, id >> 4, As0, As1, Bs0, Bs1, cnb, gbT, gamma_b, x, xstat, xbf, 1024, 2048, 512);
  } else {
    id -= 256;
    gemm_body<0, 1, 2>(id & 31, id >> 5, As0, As1, Bs0, Bs1, cb, cgT, b_cg, nullptr, nullptr, cglin, 1024, 1024, 512);
  }
}

// ---------------------------------------------------------------------------
// Weight transpose body: in f32 [K,N] -> out bf16 [N,K], optional interleave.
// ---------------------------------------------------------------------------
__device__ __forceinline__ void wtrans_body(
    int id, float (*T)[65],
    const float* __restrict__ gamma_w, const float* __restrict__ beta_w,
    const float* __restrict__ w_cg, const float* __restrict__ w_q,
    const float* __restrict__ w_kv, const float* __restrict__ w_og,
    const float* __restrict__ w_out, const float* __restrict__ w_a,
    const float* __restrict__ w_b2, const float* __restrict__ w_o,
    u16* __restrict__ gbT, u16* __restrict__ cgT, u16* __restrict__ qkvT,
    u16* __restrict__ woT, u16* __restrict__ abT, u16* __restrict__ oT) {
  const float* src; u16* dst; int K, N, ptype = 0;
  if (id < 128)       { src = gamma_w; dst = gbT;  K = 512;  N = 1024; ptype = 1; }
  else if (id < 256)  { src = beta_w;  dst = gbT;  K = 512;  N = 1024; ptype = 2; id -= 128; }
  else if (id < 384)  { src = w_cg;    dst = cgT;  K = 512;  N = 1024; id -= 256; }
  else if (id < 640)  { src = w_q;     dst = qkvT; K = 1024; N = 1024; id -= 384; }
  else if (id < 1152) { src = w_kv;    dst = qkvT + (size_t)1024 * 1024; K = 1024; N = 2048; id -= 640; }
  else if (id < 1408) { src = w_og;    dst = qkvT + (size_t)3072 * 1024; K = 1024; N = 1024; id -= 1152; }
  else if (id < 1664) { src = w_out;   dst = woT;  K = 1024; N = 1024; id -= 1408; }
  else if (id < 2176) { src = w_a;     dst = abT;  K = 1024; N = 2048; ptype = 1; id -= 1664; }
  else if (id < 2688) { src = w_b2;    dst = abT;  K = 1024; N = 2048; ptype = 2; id -= 2176; }
  else                { src = w_o;     dst = oT;   K = 2048; N = 1024; id -= 2688; }
  const int tk = K >> 6;
  const int k0 = (id % tk) * 64, n0 = (id / tk) * 64;

  const int t = threadIdx.x;
#pragma unroll
  for (int i = 0; i < 4; ++i) {
    int idx = i * 256 + t;
    int kr = idx >> 4, c4 = (idx & 15) << 2;
    f32x4 v = *(const f32x4*)(src + (size_t)(k0 + kr) * N + n0 + c4);
    T[kr][c4] = v.x; T[kr][c4 + 1] = v.y; T[kr][c4 + 2] = v.z; T[kr][c4 + 3] = v.w;
  }
  __syncthreads();
#pragma unroll
  for (int i = 0; i < 2; ++i) {
    int idx = i * 256 + t;
    int n = idx >> 3, kc = (idx & 7) << 3;
    u32x4 o;
#pragma unroll
    for (int j = 0; j < 4; ++j) {
      u16 lo = f2bf(T[kc + 2 * j][n]);
      u16 hi = f2bf(T[kc + 2 * j + 1][n]);
      o[j] = (u32)lo | ((u32)hi << 16);
    }
    int ng = n0 + n;
    int r = (ptype == 0) ? ng : (((ng >> 4) << 5) + (ng & 15) + ((ptype == 2) ? 16 : 0));
    *(u32x4*)(dst + (size_t)r * K + k0 + kc) = o;
  }
}

__device__ __forceinline__ void block_reduce2_256(float& s, float& q, float* sb, int t) {
#pragma unroll
  for (int m = 1; m < 64; m <<= 1) { s += __shfl_xor(s, m); q += __shfl_xor(q, m); }
  if ((t & 63) == 0) { sb[(t >> 6) * 2] = s; sb[(t >> 6) * 2 + 1] = q; }
  __syncthreads();
  s = sb[0] + sb[2] + sb[4] + sb[6];
  q = sb[1] + sb[3] + sb[5] + sb[7];
}

// ---------------------------------------------------------------------------
// x row stats + LN(cond)->bf16 + raw cond->bf16 (one block per row)
// ---------------------------------------------------------------------------
__device__ __forceinline__ void ln_cond_x_body(int row, const float* __restrict__ cond,
                                               const float* __restrict__ x,
                                               u16* __restrict__ cnb, u16* __restrict__ cb,
                                               float* __restrict__ xstat) {
  const int t = threadIdx.x;
  __shared__ float sb[8];
  f32x4 xv = *(const f32x4*)(x + (size_t)row * 1024 + t * 4);
  float s = xv.x + xv.y + xv.z + xv.w;
  float q = xv.x * xv.x + xv.y * xv.y + xv.z * xv.z + xv.w * xv.w;
  block_reduce2_256(s, q, sb, t);
  if (t == 0) {
    float mean = s * (1.0f / 1024.0f);
    float var = q * (1.0f / 1024.0f) - mean * mean;
    xstat[2 * row] = mean;
    xstat[2 * row + 1] = rsqrtf(var + 1e-5f);
  }
  __syncthreads();
  f32x4 cv = {0.0f, 0.0f, 0.0f, 0.0f};
  if (t < 128) cv = *(const f32x4*)(cond + (size_t)row * 512 + t * 4);
  float s2 = cv.x + cv.y + cv.z + cv.w;
  float q2 = cv.x * cv.x + cv.y * cv.y + cv.z * cv.z + cv.w * cv.w;
  block_reduce2_256(s2, q2, sb, t);
  if (t < 128) {
    float mean = s2 * (1.0f / 512.0f);
    float var = q2 * (1.0f / 512.0f) - mean * mean;
    float rinv = rsqrtf(var + 1e-5f);
    u16x4 on, oc;
    on.x = f2bf((cv.x - mean) * rinv); on.y = f2bf((cv.y - mean) * rinv);
    on.z = f2bf((cv.z - mean) * rinv); on.w = f2bf((cv.w - mean) * rinv);
    oc.x = f2bf(cv.x); oc.y = f2bf(cv.y); oc.z = f2bf(cv.z); oc.w = f2bf(cv.w);
    *(u16x4*)(cnb + (size_t)row * 512 + t * 4) = on;
    *(u16x4*)(cb + (size_t)row * 512 + t * 4) = oc;
  }
}

// ---------------------------------------------------------------------------
// Pair bias body: bias[b,h,q,k] = LN(z[b,q,k,:])·w_b[:,h] + mask -> bf16
// ---------------------------------------------------------------------------
__device__ __forceinline__ void biasz_body(int bq, const float* __restrict__ z,
                                           const float* __restrict__ zs, const float* __restrict__ zbias,
                                           const float* __restrict__ wb, const float* __restrict__ xmask,
                                           u16* __restrict__ biasb) {
  const int b = bq >> 9, qi = bq & 511;
  const int t = threadIdx.x, wave = t >> 6, lane = t & 63;
  const int lrow = lane & 15, lgrp = lane >> 4;

  float zsv[32], zbv[32];
  Frag wf[4];
#pragma unroll
  for (int j = 0; j < 4; ++j) {
#pragma unroll
    for (int e2 = 0; e2 < 4; ++e2) {
      int c0 = 32 * j + lgrp * 8 + e2 * 2;
      zsv[j * 8 + e2 * 2] = zs[c0];
      zsv[j * 8 + e2 * 2 + 1] = zs[c0 + 1];
      zbv[j * 8 + e2 * 2] = zbias[c0];
      zbv[j * 8 + e2 * 2 + 1] = zbias[c0 + 1];
      u16 lo = f2bf(wb[c0 * 16 + lrow]);
      u16 hi = f2bf(wb[(c0 + 1) * 16 + lrow]);
      wf[j].u[e2] = (u32)lo | ((u32)hi << 16);
    }
  }
  float qm = xmask[b * 512 + qi];
  float qadd = 1.0e8f * (qm - 1.0f);
  const float* zrowbase = z + ((size_t)(b * 512 + qi)) * 512 * 128;

  for (int kt = wave; kt < 32; kt += 4) {
    const float* zp = zrowbase + (size_t)(kt * 16 + lrow) * 128;
    float zv[32];
#pragma unroll
    for (int j = 0; j < 4; ++j) {
      f32x4 v0 = *(const f32x4*)(zp + 32 * j + lgrp * 8);
      f32x4 v1 = *(const f32x4*)(zp + 32 * j + lgrp * 8 + 4);
      zv[j * 8 + 0] = v0.x; zv[j * 8 + 1] = v0.y; zv[j * 8 + 2] = v0.z; zv[j * 8 + 3] = v0.w;
      zv[j * 8 + 4] = v1.x; zv[j * 8 + 5] = v1.y; zv[j * 8 + 6] = v1.z; zv[j * 8 + 7] = v1.w;
    }
    float s = 0.0f, q2 = 0.0f;
#pragma unroll
    for (int i = 0; i < 32; ++i) { s += zv[i]; q2 += zv[i] * zv[i]; }
    s += __shfl_xor(s, 16); q2 += __shfl_xor(q2, 16);
    s += __shfl_xor(s, 32); q2 += __shfl_xor(q2, 32);
    float mean = s * (1.0f / 128.0f);
    float var = q2 * (1.0f / 128.0f) - mean * mean;
    float rinv = rsqrtf(var + 1e-5f);

    f32x4 acc = {0.0f, 0.0f, 0.0f, 0.0f};
#pragma unroll
    for (int j = 0; j < 4; ++j) {
      Frag afr;
#pragma unroll
      for (int e2 = 0; e2 < 4; ++e2) {
        float zn0 = (zv[j * 8 + e2 * 2] - mean) * rinv * zsv[j * 8 + e2 * 2] + zbv[j * 8 + e2 * 2];
        float zn1 = (zv[j * 8 + e2 * 2 + 1] - mean) * rinv * zsv[j * 8 + e2 * 2 + 1] + zbv[j * 8 + e2 * 2 + 1];
        afr.u[e2] = (u32)f2bf(zn0) | ((u32)f2bf(zn1) << 16);
      }
      acc = __builtin_amdgcn_mfma_f32_16x16x32_bf16(afr.b, wf[j].b, acc, 0, 0, 0);
    }

    int kbase = kt * 16 + lgrp * 4;
    float v0 = acc[0] + qadd + 1.0e8f * (xmask[b * 512 + kbase + 0] - 1.0f);
    float v1 = acc[1] + qadd + 1.0e8f * (xmask[b * 512 + kbase + 1] - 1.0f);
    float v2 = acc[2] + qadd + 1.0e8f * (xmask[b * 512 + kbase + 2] - 1.0f);
    float v3 = acc[3] + qadd + 1.0e8f * (xmask[b * 512 + kbase + 3] - 1.0f);
    u16* outp = biasb + (((size_t)(b * 16 + lrow) * 512 + qi) * 512 + kbase);
    *(u32*)outp       = (u32)f2bf(v0) | ((u32)f2bf(v1) << 16);
    *(u32*)(outp + 2) = (u32)f2bf(v2) | ((u32)f2bf(v3) << 16);
  }
}

// ---------------------------------------------------------------------------
// mega0: biasz (1024) ∪ wtrans (3200) ∪ ln_cond_x (1024) — all independent.
// biasz blocks first (longest; streams z while transposes fill spare CUs).
// ---------------------------------------------------------------------------
__global__ __launch_bounds__(256) void mega0(
    const float* __restrict__ z, const float* __restrict__ zs, const float* __restrict__ zbias,
    const float* __restrict__ wb, const float* __restrict__ xmask, u16* __restrict__ biasb,
    const float* __restrict__ gamma_w, const float* __restrict__ beta_w,
    const float* __restrict__ w_cg, const float* __restrict__ w_q,
    const float* __restrict__ w_kv, const float* __restrict__ w_og,
    const float* __restrict__ w_out, const float* __restrict__ w_a,
    const float* __restrict__ w_b2, const float* __restrict__ w_o,
    u16* __restrict__ gbT, u16* __restrict__ cgT, u16* __restrict__ qkvT,
    u16* __restrict__ woT, u16* __restrict__ abT, u16* __restrict__ oT,
    const float* __restrict__ cond, const float* __restrict__ x,
    u16* __restrict__ cnb, u16* __restrict__ cb, float* __restrict__ xstat) {
  __shared__ float Tsh[64][65];
  int id = blockIdx.x;
  if (id < 1024) {
    biasz_body(id, z, zs, zbias, wb, xmask, biasb);
  } else if (id < 4224) {
    wtrans_body(id - 1024, Tsh, gamma_w, beta_w, w_cg, w_q, w_kv, w_og, w_out, w_a, w_b2, w_o,
                gbT, cgT, qkvT, woT, abT, oT);
  } else {
    ln_cond_x_body(id - 4224, cond, x, cnb, cb, xstat);
  }
}

// ---------------------------------------------------------------------------
// Flash attention, 512 blocks x 128 threads (2 waves), 32 q-rows per block.
// Two independent blocks per CU -> cross-block TLP hides barrier drains
// (R7/R8 mechanism applied to attn). K/V/bias staged via LDS with T14
// tile prefetch. Fused epilogue: gu = (O/l) * sigmoid(og) -> bf16.
// ---------------------------------------------------------------------------
__global__ __launch_bounds__(128) void attn(const u16* __restrict__ qkv, const u16* __restrict__ vT,
                                            const u16* __restrict__ biasb, u16* __restrict__ gub) {
  __shared__ u16 Ks[64 * 64];
  __shared__ u16 Vs[64 * 64];
  __shared__ u16 Ps[2][16 * 64];
  __shared__ u16 Bbs[32 * 64];
  const int t = threadIdx.x, wave = t >> 6, lane = t & 63;
  const int lrow = lane & 15, lgrp = lane >> 4;
  const int bh = blockIdx.x >> 4, qt = blockIdx.x & 15;
  const int b = bh >> 4, h = bh & 15;
  const int q0 = qt * 32 + wave * 16;

  Frag qf[2];
#pragma unroll
  for (int ks = 0; ks < 2; ++ks) {
    int tok = b * 512 + q0 + lrow;
    qf[ks].u = *(const u32x4*)(qkv + (size_t)tok * 4096 + h * 64 + ks * 32 + lgrp * 8);
  }
  f32x4 oacc[4] = {};
  float mrun[4], lrun[4];
#pragma unroll
  for (int rg = 0; rg < 4; ++rg) { mrun[rg] = -3.0e38f; lrun[rg] = 0.0f; }

  // K/V staging: 4 chunks of 2048B (128 thr x 16B); row r, swizzled col c.
  int kr_[4], kc_[4];
#pragma unroll
  for (int i = 0; i < 4; ++i) {
    int o = i * 2048 + t * 16;
    kr_[i] = o >> 7;
    int s = (o >> 4) & 7;
    kc_[i] = (s ^ (kr_[i] & 7)) << 3;
  }
  // bias staging: 2 chunks (32 rows x 128B)
  const int bs0 = t & 7;
  int br_[2] = { (t >> 3), 16 + (t >> 3) };
  const u16* bbase = biasb + ((size_t)bh * 512 + qt * 32) * 512;

  const u16* kp[4]; const u16* vp[4]; const u16* bp[2];
#pragma unroll
  for (int i = 0; i < 4; ++i) {
    kp[i] = qkv + (size_t)(b * 512 + kr_[i]) * 4096 + 1024 + h * 64 + kc_[i];
    vp[i] = vT + (size_t)(bh * 64 + kr_[i]) * 512 + kc_[i];
  }
#pragma unroll
  for (int i = 0; i < 2; ++i) bp[i] = bbase + (size_t)br_[i] * 512 + bs0 * 8;

  // prefetch tile 0
  u32x4 kv[4], vv[4], bb[2];
#pragma unroll
  for (int i = 0; i < 4; ++i) { kv[i] = *(const u32x4*)(kp[i]); vv[i] = *(const u32x4*)(vp[i]); }
#pragma unroll
  for (int i = 0; i < 2; ++i) bb[i] = *(const u32x4*)(bp[i]);

  for (int kt = 0; kt < 8; ++kt) {
    __syncthreads();
#pragma unroll
    for (int i = 0; i < 4; ++i) {
      *(u32x4*)((char*)Ks + i * 2048 + t * 16) = kv[i];
      *(u32x4*)((char*)Vs + i * 2048 + t * 16) = vv[i];
    }
#pragma unroll
    for (int i = 0; i < 2; ++i)
      *(u32x4*)((char*)Bbs + br_[i] * 128 + ((bs0 ^ (br_[i] & 7)) << 4)) = bb[i];
    __syncthreads();

    // issue next tile's loads now -> latency hides under compute below
    {
      int k1g = ((kt + 1) & 7) * 64;
#pragma unroll
      for (int i = 0; i < 4; ++i) {
        kv[i] = *(const u32x4*)(kp[i] + (size_t)k1g * 4096);
        vv[i] = *(const u32x4*)(vp[i] + k1g);
      }
#pragma unroll
      for (int i = 0; i < 2; ++i) bb[i] = *(const u32x4*)(bp[i] + k1g);
    }

    f32x4 sf[4] = {};
#pragma unroll
    for (int ks = 0; ks < 2; ++ks) {
#pragma unroll
      for (int ni = 0; ni < 4; ++ni) {
        int row = ni * 16 + lrow;
        int slot = (ks * 4 + lgrp) ^ (row & 7);
        Frag kf;
        kf.u = *(const u32x4*)((const char*)Ks + row * 128 + (slot << 4));
        sf[ni] = __builtin_amdgcn_mfma_f32_16x16x32_bf16(qf[ks].b, kf.b, sf[ni], 0, 0, 0);
      }
    }

    float sv[4][4];
#pragma unroll
    for (int ni = 0; ni < 4; ++ni) {
#pragma unroll
      for (int rg = 0; rg < 4; ++rg) {
        int qlocal = wave * 16 + lgrp * 4 + rg;
        int k = ni * 16 + lrow;
        float bvv = bf2f(*(const u16*)((const char*)Bbs + qlocal * 128 +
                                       (((k >> 3) ^ (qlocal & 7)) << 4) + (k & 7) * 2));
        sv[ni][rg] = sf[ni][rg] * 0.125f + bvv;
      }
    }
    float mnew[4], fac[4];
#pragma unroll
    for (int rg = 0; rg < 4; ++rg) {
      float tm = fmaxf(fmaxf(sv[0][rg], sv[1][rg]), fmaxf(sv[2][rg], sv[3][rg]));
      tm = fmaxf(tm, __shfl_xor(tm, 1));
      tm = fmaxf(tm, __shfl_xor(tm, 2));
      tm = fmaxf(tm, __shfl_xor(tm, 4));
      tm = fmaxf(tm, __shfl_xor(tm, 8));
      mnew[rg] = fmaxf(mrun[rg], tm);
      fac[rg] = __expf(mrun[rg] - mnew[rg]);
      mrun[rg] = mnew[rg];
    }
    float psum[4] = {0.0f, 0.0f, 0.0f, 0.0f};
#pragma unroll
    for (int ni = 0; ni < 4; ++ni)
#pragma unroll
      for (int rg = 0; rg < 4; ++rg) {
        float p = __expf(sv[ni][rg] - mnew[rg]);
        sv[ni][rg] = p;
        psum[rg] += p;
      }
#pragma unroll
    for (int rg = 0; rg < 4; ++rg) {
      float ps = psum[rg];
      ps += __shfl_xor(ps, 1); ps += __shfl_xor(ps, 2);
      ps += __shfl_xor(ps, 4); ps += __shfl_xor(ps, 8);
      lrun[rg] = lrun[rg] * fac[rg] + ps;
#pragma unroll
      for (int nd = 0; nd < 4; ++nd) oacc[nd][rg] *= fac[rg];
    }
#pragma unroll
    for (int ni = 0; ni < 4; ++ni)
#pragma unroll
      for (int rg = 0; rg < 4; ++rg) {
        int prow = lgrp * 4 + rg;
        int col = ni * 16 + lrow;
        int slot = (col >> 3) ^ (prow & 7);
        *(u16*)((char*)Ps[wave] + prow * 128 + (slot << 4) + (col & 7) * 2) = f2bf(sv[ni][rg]);
      }
    Frag paf[2];
#pragma unroll
    for (int ks = 0; ks < 2; ++ks) {
      int slot = (ks * 4 + lgrp) ^ (lrow & 7);
      paf[ks].u = *(const u32x4*)((const char*)Ps[wave] + lrow * 128 + (slot << 4));
    }
#pragma unroll
    for (int ks = 0; ks < 2; ++ks)
#pragma unroll
      for (int nd = 0; nd < 4; ++nd) {
        int row = nd * 16 + lrow;
        int slot = (ks * 4 + lgrp) ^ (row & 7);
        Frag vf;
        vf.u = *(const u32x4*)((const char*)Vs + row * 128 + (slot << 4));
        oacc[nd] = __builtin_amdgcn_mfma_f32_16x16x32_bf16(paf[ks].b, vf.b, oacc[nd], 0, 0, 0);
      }
  }

#pragma unroll
  for (int nd = 0; nd < 4; ++nd) {
#pragma unroll
    for (int rg = 0; rg < 4; ++rg) {
      int tok = b * 512 + q0 + lgrp * 4 + rg;
      int col = h * 64 + nd * 16 + lrow;
      float og = bf2f(qkv[(size_t)tok * 4096 + 3072 + col]);
      float val = oacc[nd][rg] / lrun[rg] * sigmoidf_(og);
      gub[(size_t)tok * 1024 + col] = f2bf(val);
    }
  }
}

// ---------------------------------------------------------------------------
// xl = LN(x1)*ffn_scale + ffn_bias (bf16)
// ---------------------------------------------------------------------------
__global__ __launch_bounds__(256) void ln_affine(const float* __restrict__ x1, const float* __restrict__ fs,
                                                 const float* __restrict__ fb, u16* __restrict__ xlb) {
  const int row = blockIdx.x;
  const int t = threadIdx.x;
  __shared__ float sb[8];
  f32x4 v = *(const f32x4*)(x1 + (size_t)row * 1024 + t * 4);
  float s = v.x + v.y + v.z + v.w;
  float q = v.x * v.x + v.y * v.y + v.z * v.z + v.w * v.w;
  block_reduce2_256(s, q, sb, t);
  float mean = s * (1.0f / 1024.0f);
  float var = q * (1.0f / 1024.0f) - mean * mean;
  float rinv = rsqrtf(var + 1e-5f);
  f32x4 fsv = *(const f32x4*)(fs + t * 4);
  f32x4 fbv = *(const f32x4*)(fb + t * 4);
  u16x4 o;
  o.x = f2bf((v.x - mean) * rinv * fsv.x + fbv.x);
  o.y = f2bf((v.y - mean) * rinv * fsv.y + fbv.y);
  o.z = f2bf((v.z - mean) * rinv * fsv.z + fbv.z);
  o.w = f2bf((v.w - mean) * rinv * fsv.w + fbv.w);
  *(u16x4*)(xlb + (size_t)row * 1024 + t * 4) = o;
}

// ---------------------------------------------------------------------------
extern "C" void kernel_launch(void* const* d_in, const int* in_sizes, int n_in,
                              void* d_out, int out_size, void* d_ws, size_t ws_size,
                              hipStream_t stream) {
  (void)in_sizes; (void)n_in; (void)out_size; (void)ws_size;
  const float* x        = (const float*)d_in[0];
  const float* cond     = (const float*)d_in[1];
  const float* z        = (const float*)d_in[2];
  const float* xmask    = (const float*)d_in[3];
  const float* gamma_w  = (const float*)d_in[4];
  const float* gamma_b  = (const float*)d_in[5];
  const float* beta_w   = (const float*)d_in[6];
  const float* z_scale  = (const float*)d_in[7];
  const float* z_bias   = (const float*)d_in[8];
  const float* w_q      = (const float*)d_in[9];
  const float* w_kv     = (const float*)d_in[10];
  const float* w_b      = (const float*)d_in[11];
  const float* w_og     = (const float*)d_in[12];
  const float* w_out    = (const float*)d_in[13];
  const float* w_cg     = (const float*)d_in[14];
  const float* b_cg     = (const float*)d_in[15];
  const float* ffn_scale= (const float*)d_in[16];
  const float* ffn_bias = (const float*)d_in[17];
  const float* w_a      = (const float*)d_in[18];
  const float* w_b2     = (const float*)d_in[19];
  const float* w_o      = (const float*)d_in[20];
  float* out = (float*)d_out;

  char* ws = (char*)d_ws;
  size_t off = 0;
  auto alloc = [&](size_t bytes) -> void* {
    void* p = ws + off;
    off += (bytes + 255) & ~(size_t)255;
    return p;
  };
  u16* cnb     = (u16*)alloc(1024 * 512 * 2);
  u16* cb      = (u16*)alloc(1024 * 512 * 2);
  float* xstat = (float*)alloc(1024 * 2 * 4);
  float* cglin = (float*)alloc((size_t)1024 * 1024 * 4);
  u16* xbf     = (u16*)alloc((size_t)1024 * 1024 * 2);
  u16* qkv     = (u16*)alloc((size_t)1024 * 4096 * 2);
  u16* vT      = (u16*)alloc((size_t)2048 * 512 * 2);
  u16* biasb   = (u16*)alloc((size_t)32 * 512 * 512 * 2);
  u16* gub     = (u16*)alloc((size_t)1024 * 1024 * 2);
  float* x1    = (float*)alloc((size_t)1024 * 1024 * 4);
  u16* xlb     = (u16*)alloc((size_t)1024 * 1024 * 2);
  u16* hb      = (u16*)alloc((size_t)1024 * 2048 * 2);
  u16* gbT     = (u16*)alloc((size_t)2048 * 512 * 2);
  u16* cgT     = (u16*)alloc((size_t)1024 * 512 * 2);
  u16* qkvT    = (u16*)alloc((size_t)4096 * 1024 * 2);
  u16* woT     = (u16*)alloc((size_t)1024 * 1024 * 2);
  u16* abT     = (u16*)alloc((size_t)4096 * 1024 * 2);
  u16* oT      = (u16*)alloc((size_t)1024 * 2048 * 2);

  // 1) biasz ∪ weight transposes ∪ (x stats + cond LN), one launch
  mega0<<<5248, 256, 0, stream>>>(
      z, z_scale, z_bias, w_b, xmask, biasb,
      gamma_w, beta_w, w_cg, w_q, w_kv, w_og, w_out, w_a, w_b2, w_o,
      gbT, cgT, qkvT, woT, abT, oT,
      cond, x, cnb, cb, xstat);

  // 2) AdaLN gemm (256) ∪ cond-gate gemm (512, NI2) -> 768 blocks, 3/CU
  gemm_adaln_cg<<<768, 256, 0, stream>>>(cnb, gbT, gamma_b, x, xstat, xbf,
                                         cb, cgT, b_cg, cglin);

  // 3) fused q|k|v|og projection; V columns transposed to vT (EPI6)
  gemm_t<6, 2, 4><<<dim3(16, 32), 256, 0, stream>>>(xbf, qkvT, (const float*)vT, nullptr, nullptr,
                                                    qkv, 1024, 4096, 1024);

  // 4) attention: 512 blocks x 128 threads -> 2 independent blocks/CU
  attn<<<512, 128, 0, stream>>>(qkv, vT, biasb, gub);

  // 5) out-proj fused with residual: x1 = x + (gub@w_out) * sigmoid(cglin)
  gemm_t<2, 1, 2><<<dim3(32, 16), 256, 0, stream>>>(gub, woT, nullptr, x, cglin, x1, 1024, 1024, 1024);

  // 6) xl = LN(x1)*ffn_scale + ffn_bias
  ln_affine<<<1024, 256, 0, stream>>>(x1, ffn_scale, ffn_bias, xlb);

  // 7) fused a|b2 FFN projection with SwiGLU epilogue (interleaved abT)
  gemm_t<4, 2, 4><<<dim3(16, 32), 256, 0, stream>>>(xlb, abT, nullptr, nullptr, nullptr, hb, 1024, 4096, 1024);

  // 8) FFN out fused with masked residual: out = x1 + (hb@w_o) * xmask[row]
  gemm_t<3, 1, 2><<<dim3(32, 16), 256, 0, stream>>>(hb, oT, nullptr, x1, xmask, out, 1024, 1024, 2048);
}

// Round 12
// 165.147 us; speedup vs baseline: 1.0167x; 1.0167x over previous
//
#include <hip/hip_runtime.h>
#include <stdint.h>

typedef unsigned short u16;
typedef unsigned int u32;
typedef __attribute__((ext_vector_type(4))) float f32x4;
typedef __attribute__((ext_vector_type(4))) unsigned int u32x4;
typedef __attribute__((ext_vector_type(4))) unsigned short u16x4;
typedef __attribute__((ext_vector_type(8))) __bf16 bf16x8;

union Frag { u32x4 u; bf16x8 b; };

__device__ __forceinline__ u16 f2bf(float x) {
  u32 u = __float_as_uint(x);
  u32 r = (u + 0x7fffu + ((u >> 16) & 1u)) >> 16;
  return (u16)r;
}
__device__ __forceinline__ float bf2f(u16 v) {
  u32 u = ((u32)v) << 16;
  return __uint_as_float(u);
}
__device__ __forceinline__ float sigmoidf_(float x) { return 1.0f / (1.0f + __expf(-x)); }

// async global->LDS, 16B per lane; LDS dest = wave-uniform base + lane*16
__device__ __forceinline__ void gload16(const void* g, void* lds) {
  __builtin_amdgcn_global_load_lds((const __attribute__((address_space(1))) unsigned int*)g,
                                   (__attribute__((address_space(3))) unsigned int*)lds, 16, 0, 0);
}

// ---------------------------------------------------------------------------
// MFMA GEMM body, BMxBN tile (BM = 32*MI, BN = 32*NI), BK=64, 256 threads
// (4 waves as 2x2). Double-buffered LDS (T3 minimum-2-phase): STAGE(t+1)
// issued BEFORE compute(t); ONE barrier per K-step. Requires K % 128 == 0.
// Session lessons:
//  R6: persistent-kernel software grid barriers cost ~25us each on 8-XCD
//      MI355X (L2 writeback+inv per device-scope fence) — relaunch is cheaper.
//  R7/R8: 1 block/CU exposes the dbuf barrier drain; size grids >= 512.
//  R9/R10/R11: biasz co-scheduling, XCD swizzle, attn 2-blocks/CU all
//      neutral — L3 absorbs cross-XCD refetch; this config is the floor.
// EPI: 0 = f32 (+bias), 1 = bf16, 2 = f32 x1 = e0 + v*sigmoid(e1) [per-elem],
//      3 = f32 out = e0 + v*e1[row]
//      4 = bf16 swiglu over interleaved 16-col pairs, width N/2   [NI4 only]
//      5 = bf16 adaln over interleaved pairs, width N/2 (e0=x,e1=xstat) [NI4]
//      6 = bf16 out, V columns (2048..3071) transposed to vT      [NI4 only]
//          (vT pointer smuggled via `bias`)
// ---------------------------------------------------------------------------
template<int EPI, int MI, int NI>
__device__ __forceinline__ void gemm_body(int bx, int by,
                                          u16* As0, u16* As1, u16* Bs0, u16* Bs1,
                                          const u16* __restrict__ A, const u16* __restrict__ Bt,
                                          const float* __restrict__ bias,
                                          const float* __restrict__ e0, const float* __restrict__ e1,
                                          void* __restrict__ Cp, int M, int N, int K) {
  constexpr int BM = 32 * MI;
  constexpr int BN = 32 * NI;
  const int t = threadIdx.x, wave = t >> 6, lane = t & 63;
  const int lrow = lane & 15, lgrp = lane >> 4;
  const int m0 = bx * BM, n0 = by * BN;
  const int wr = (wave >> 1) * (16 * MI), wc = (wave & 1) * (16 * NI);

  const int srow = wave * 8 + (lane >> 3);
  const int scol = (((lane & 7) ^ (lane >> 3)) << 3);
  const u16* Ab = A + (size_t)(m0 + srow) * K + scol;
  const u16* Bb = Bt + (size_t)(n0 + srow) * K + scol;

  f32x4 acc[MI][NI] = {};

  auto stage = [&](int k0, u16* Asd, u16* Bsd) {
#pragma unroll
    for (int i = 0; i < MI; ++i) gload16(Ab + (size_t)i * 32 * K + k0, Asd + wave * 512 + i * 2048);
#pragma unroll
    for (int i = 0; i < NI; ++i) gload16(Bb + (size_t)i * 32 * K + k0, Bsd + wave * 512 + i * 2048);
  };
  auto compute = [&](const u16* Asr, const u16* Bsr) {
#pragma unroll
    for (int ks = 0; ks < 2; ++ks) {
      Frag af[MI], bf4[NI];
#pragma unroll
      for (int mi = 0; mi < MI; ++mi) {
        int row = wr + mi * 16 + lrow;
        int slot = ((ks << 2) + lgrp) ^ (row & 7);
        af[mi].u = *(const u32x4*)((const char*)Asr + row * 128 + (slot << 4));
      }
#pragma unroll
      for (int ni = 0; ni < NI; ++ni) {
        int row = wc + ni * 16 + lrow;
        int slot = ((ks << 2) + lgrp) ^ (row & 7);
        bf4[ni].u = *(const u32x4*)((const char*)Bsr + row * 128 + (slot << 4));
      }
#pragma unroll
      for (int mi = 0; mi < MI; ++mi)
#pragma unroll
        for (int ni = 0; ni < NI; ++ni)
          acc[mi][ni] = __builtin_amdgcn_mfma_f32_16x16x32_bf16(af[mi].b, bf4[ni].b, acc[mi][ni], 0, 0, 0);
    }
  };

  stage(0, As0, Bs0);
  __syncthreads();
  for (int k0 = 0; k0 < K; k0 += 128) {
    stage(k0 + 64, As1, Bs1);
    compute(As0, Bs0);
    __syncthreads();
    if (k0 + 128 < K) stage(k0 + 128, As0, Bs0);
    compute(As1, Bs1);
    __syncthreads();
  }

  if constexpr (EPI == 4 || EPI == 5) {
    const int half = N >> 1;
#pragma unroll
    for (int mi = 0; mi < MI; ++mi) {
#pragma unroll
      for (int np = 0; np < 2; ++np) {
        int j = ((n0 + wc) >> 1) + np * 16 + lrow;
        float bj = 0.0f;
        if (EPI == 5) bj = bias[j];
#pragma unroll
        for (int rg = 0; rg < 4; ++rg) {
          int row = m0 + wr + mi * 16 + lgrp * 4 + rg;
          float a = acc[mi][2 * np][rg];
          float b = acc[mi][2 * np + 1][rg];
          float val;
          if constexpr (EPI == 4) {
            val = a * sigmoidf_(a) * b;
          } else {
            float mean = e1[2 * row], rinv = e1[2 * row + 1];
            float lnx = (e0[(size_t)row * half + j] - mean) * rinv;
            val = lnx * sigmoidf_(a + bj) + b;
          }
          ((u16*)Cp)[(size_t)row * half + j] = f2bf(val);
        }
      }
    }
  } else if constexpr (EPI == 6) {
    u16* vTp = (u16*)bias;  // smuggled vT pointer
    const bool isv = (n0 >= 2048) && (n0 < 3072);
#pragma unroll
    for (int mi = 0; mi < MI; ++mi) {
#pragma unroll
      for (int ni = 0; ni < NI; ++ni) {
        int col = n0 + wc + ni * 16 + lrow;
        int rowb = m0 + wr + mi * 16 + lgrp * 4;
        if (isv) {
          int h = (col - 2048) >> 6, d = col & 63;
          int b = rowb >> 9, n = rowb & 511;
          u16x4 o;
#pragma unroll
          for (int rg = 0; rg < 4; ++rg) o[rg] = f2bf(acc[mi][ni][rg]);
          *(u16x4*)(vTp + ((size_t)((b * 16 + h) * 64 + d)) * 512 + n) = o;
        } else {
#pragma unroll
          for (int rg = 0; rg < 4; ++rg)
            ((u16*)Cp)[(size_t)(rowb + rg) * N + col] = f2bf(acc[mi][ni][rg]);
        }
      }
    }
  } else {
#pragma unroll
    for (int mi = 0; mi < MI; ++mi) {
#pragma unroll
      for (int ni = 0; ni < NI; ++ni) {
        int col = n0 + wc + ni * 16 + lrow;
        float bv = 0.0f;
        if (EPI == 0 && bias) bv = bias[col];
#pragma unroll
        for (int rg = 0; rg < 4; ++rg) {
          int row = m0 + wr + mi * 16 + lgrp * 4 + rg;
          size_t idx = (size_t)row * N + col;
          float v = acc[mi][ni][rg];
          if constexpr (EPI == 0)      ((float*)Cp)[idx] = v + bv;
          else if constexpr (EPI == 1) ((u16*)Cp)[idx] = f2bf(v);
          else if constexpr (EPI == 2) ((float*)Cp)[idx] = e0[idx] + v * sigmoidf_(e1[idx]);
          else                         ((float*)Cp)[idx] = e0[idx] + v * e1[row];
        }
      }
    }
  }
  (void)M;
}

template<int EPI, int MI, int NI>
__global__ __launch_bounds__(256) void gemm_t(const u16* __restrict__ A, const u16* __restrict__ Bt,
                                              const float* __restrict__ bias,
                                              const float* __restrict__ e0, const float* __restrict__ e1,
                                              void* __restrict__ Cp, int M, int N, int K) {
  __shared__ u16 As0[32 * MI * 64], As1[32 * MI * 64];
  __shared__ u16 Bs0[32 * NI * 64], Bs1[32 * NI * 64];
  gemm_body<EPI, MI, NI>(blockIdx.x, blockIdx.y, As0, As1, Bs0, Bs1, A, Bt, bias, e0, e1, Cp, M, N, K);
}

// ---------------------------------------------------------------------------
// Fused adaln-gemm (EPI5,MI2,NI4; 256 blocks) + cond-gate gemm (EPI0,MI1,NI2;
// 512 blocks) -> 768 blocks = 3/CU mix
// ---------------------------------------------------------------------------
__global__ __launch_bounds__(256) void gemm_adaln_cg(
    const u16* __restrict__ cnb, const u16* __restrict__ gbT, const float* __restrict__ gamma_b,
    const float* __restrict__ x, const float* __restrict__ xstat, u16* __restrict__ xbf,
    const u16* __restrict__ cb, const u16* __restrict__ cgT, const float* __restrict__ b_cg,
    float* __restrict__ cglin) {
  __shared__ u16 As0[64 * 64], As1[64 * 64];
  __shared__ u16 Bs0[128 * 64], Bs1[128 * 64];
  int id = blockIdx.x;
  if (id < 256) {
    gemm_body<5, 2, 4>(id & 15, id >> 4, As0, As1, Bs0, Bs1, cnb, gbT, gamma_b, x, xstat, xbf, 1024, 2048, 512);
  } else {
    id -= 256;
    gemm_body<0, 1, 2>(id & 31, id >> 5, As0, As1, Bs0, Bs1, cb, cgT, b_cg, nullptr, nullptr, cglin, 1024, 1024, 512);
  }
}

// ---------------------------------------------------------------------------
// Weight transpose body: in f32 [K,N] -> out bf16 [N,K], optional interleave.
// ---------------------------------------------------------------------------
__device__ __forceinline__ void wtrans_body(
    int id, float (*T)[65],
    const float* __restrict__ gamma_w, const float* __restrict__ beta_w,
    const float* __restrict__ w_cg, const float* __restrict__ w_q,
    const float* __restrict__ w_kv, const float* __restrict__ w_og,
    const float* __restrict__ w_out, const float* __restrict__ w_a,
    const float* __restrict__ w_b2, const float* __restrict__ w_o,
    u16* __restrict__ gbT, u16* __restrict__ cgT, u16* __restrict__ qkvT,
    u16* __restrict__ woT, u16* __restrict__ abT, u16* __restrict__ oT) {
  const float* src; u16* dst; int K, N, ptype = 0;
  if (id < 128)       { src = gamma_w; dst = gbT;  K = 512;  N = 1024; ptype = 1; }
  else if (id < 256)  { src = beta_w;  dst = gbT;  K = 512;  N = 1024; ptype = 2; id -= 128; }
  else if (id < 384)  { src = w_cg;    dst = cgT;  K = 512;  N = 1024; id -= 256; }
  else if (id < 640)  { src = w_q;     dst = qkvT; K = 1024; N = 1024; id -= 384; }
  else if (id < 1152) { src = w_kv;    dst = qkvT + (size_t)1024 * 1024; K = 1024; N = 2048; id -= 640; }
  else if (id < 1408) { src = w_og;    dst = qkvT + (size_t)3072 * 1024; K = 1024; N = 1024; id -= 1152; }
  else if (id < 1664) { src = w_out;   dst = woT;  K = 1024; N = 1024; id -= 1408; }
  else if (id < 2176) { src = w_a;     dst = abT;  K = 1024; N = 2048; ptype = 1; id -= 1664; }
  else if (id < 2688) { src = w_b2;    dst = abT;  K = 1024; N = 2048; ptype = 2; id -= 2176; }
  else                { src = w_o;     dst = oT;   K = 2048; N = 1024; id -= 2688; }
  const int tk = K >> 6;
  const int k0 = (id % tk) * 64, n0 = (id / tk) * 64;

  const int t = threadIdx.x;
#pragma unroll
  for (int i = 0; i < 4; ++i) {
    int idx = i * 256 + t;
    int kr = idx >> 4, c4 = (idx & 15) << 2;
    f32x4 v = *(const f32x4*)(src + (size_t)(k0 + kr) * N + n0 + c4);
    T[kr][c4] = v.x; T[kr][c4 + 1] = v.y; T[kr][c4 + 2] = v.z; T[kr][c4 + 3] = v.w;
  }
  __syncthreads();
#pragma unroll
  for (int i = 0; i < 2; ++i) {
    int idx = i * 256 + t;
    int n = idx >> 3, kc = (idx & 7) << 3;
    u32x4 o;
#pragma unroll
    for (int j = 0; j < 4; ++j) {
      u16 lo = f2bf(T[kc + 2 * j][n]);
      u16 hi = f2bf(T[kc + 2 * j + 1][n]);
      o[j] = (u32)lo | ((u32)hi << 16);
    }
    int ng = n0 + n;
    int r = (ptype == 0) ? ng : (((ng >> 4) << 5) + (ng & 15) + ((ptype == 2) ? 16 : 0));
    *(u32x4*)(dst + (size_t)r * K + k0 + kc) = o;
  }
}

__device__ __forceinline__ void block_reduce2_256(float& s, float& q, float* sb, int t) {
#pragma unroll
  for (int m = 1; m < 64; m <<= 1) { s += __shfl_xor(s, m); q += __shfl_xor(q, m); }
  if ((t & 63) == 0) { sb[(t >> 6) * 2] = s; sb[(t >> 6) * 2 + 1] = q; }
  __syncthreads();
  s = sb[0] + sb[2] + sb[4] + sb[6];
  q = sb[1] + sb[3] + sb[5] + sb[7];
}

// ---------------------------------------------------------------------------
// x row stats + LN(cond)->bf16 + raw cond->bf16 (one block per row)
// ---------------------------------------------------------------------------
__device__ __forceinline__ void ln_cond_x_body(int row, const float* __restrict__ cond,
                                               const float* __restrict__ x,
                                               u16* __restrict__ cnb, u16* __restrict__ cb,
                                               float* __restrict__ xstat) {
  const int t = threadIdx.x;
  __shared__ float sb[8];
  f32x4 xv = *(const f32x4*)(x + (size_t)row * 1024 + t * 4);
  float s = xv.x + xv.y + xv.z + xv.w;
  float q = xv.x * xv.x + xv.y * xv.y + xv.z * xv.z + xv.w * xv.w;
  block_reduce2_256(s, q, sb, t);
  if (t == 0) {
    float mean = s * (1.0f / 1024.0f);
    float var = q * (1.0f / 1024.0f) - mean * mean;
    xstat[2 * row] = mean;
    xstat[2 * row + 1] = rsqrtf(var + 1e-5f);
  }
  __syncthreads();
  f32x4 cv = {0.0f, 0.0f, 0.0f, 0.0f};
  if (t < 128) cv = *(const f32x4*)(cond + (size_t)row * 512 + t * 4);
  float s2 = cv.x + cv.y + cv.z + cv.w;
  float q2 = cv.x * cv.x + cv.y * cv.y + cv.z * cv.z + cv.w * cv.w;
  block_reduce2_256(s2, q2, sb, t);
  if (t < 128) {
    float mean = s2 * (1.0f / 512.0f);
    float var = q2 * (1.0f / 512.0f) - mean * mean;
    float rinv = rsqrtf(var + 1e-5f);
    u16x4 on, oc;
    on.x = f2bf((cv.x - mean) * rinv); on.y = f2bf((cv.y - mean) * rinv);
    on.z = f2bf((cv.z - mean) * rinv); on.w = f2bf((cv.w - mean) * rinv);
    oc.x = f2bf(cv.x); oc.y = f2bf(cv.y); oc.z = f2bf(cv.z); oc.w = f2bf(cv.w);
    *(u16x4*)(cnb + (size_t)row * 512 + t * 4) = on;
    *(u16x4*)(cb + (size_t)row * 512 + t * 4) = oc;
  }
}

// ---------------------------------------------------------------------------
// Pair bias body: bias[b,h,q,k] = LN(z[b,q,k,:])·w_b[:,h] + mask -> bf16
// ---------------------------------------------------------------------------
__device__ __forceinline__ void biasz_body(int bq, const float* __restrict__ z,
                                           const float* __restrict__ zs, const float* __restrict__ zbias,
                                           const float* __restrict__ wb, const float* __restrict__ xmask,
                                           u16* __restrict__ biasb) {
  const int b = bq >> 9, qi = bq & 511;
  const int t = threadIdx.x, wave = t >> 6, lane = t & 63;
  const int lrow = lane & 15, lgrp = lane >> 4;

  float zsv[32], zbv[32];
  Frag wf[4];
#pragma unroll
  for (int j = 0; j < 4; ++j) {
#pragma unroll
    for (int e2 = 0; e2 < 4; ++e2) {
      int c0 = 32 * j + lgrp * 8 + e2 * 2;
      zsv[j * 8 + e2 * 2] = zs[c0];
      zsv[j * 8 + e2 * 2 + 1] = zs[c0 + 1];
      zbv[j * 8 + e2 * 2] = zbias[c0];
      zbv[j * 8 + e2 * 2 + 1] = zbias[c0 + 1];
      u16 lo = f2bf(wb[c0 * 16 + lrow]);
      u16 hi = f2bf(wb[(c0 + 1) * 16 + lrow]);
      wf[j].u[e2] = (u32)lo | ((u32)hi << 16);
    }
  }
  float qm = xmask[b * 512 + qi];
  float qadd = 1.0e8f * (qm - 1.0f);
  const float* zrowbase = z + ((size_t)(b * 512 + qi)) * 512 * 128;

  for (int kt = wave; kt < 32; kt += 4) {
    const float* zp = zrowbase + (size_t)(kt * 16 + lrow) * 128;
    float zv[32];
#pragma unroll
    for (int j = 0; j < 4; ++j) {
      f32x4 v0 = *(const f32x4*)(zp + 32 * j + lgrp * 8);
      f32x4 v1 = *(const f32x4*)(zp + 32 * j + lgrp * 8 + 4);
      zv[j * 8 + 0] = v0.x; zv[j * 8 + 1] = v0.y; zv[j * 8 + 2] = v0.z; zv[j * 8 + 3] = v0.w;
      zv[j * 8 + 4] = v1.x; zv[j * 8 + 5] = v1.y; zv[j * 8 + 6] = v1.z; zv[j * 8 + 7] = v1.w;
    }
    float s = 0.0f, q2 = 0.0f;
#pragma unroll
    for (int i = 0; i < 32; ++i) { s += zv[i]; q2 += zv[i] * zv[i]; }
    s += __shfl_xor(s, 16); q2 += __shfl_xor(q2, 16);
    s += __shfl_xor(s, 32); q2 += __shfl_xor(q2, 32);
    float mean = s * (1.0f / 128.0f);
    float var = q2 * (1.0f / 128.0f) - mean * mean;
    float rinv = rsqrtf(var + 1e-5f);

    f32x4 acc = {0.0f, 0.0f, 0.0f, 0.0f};
#pragma unroll
    for (int j = 0; j < 4; ++j) {
      Frag afr;
#pragma unroll
      for (int e2 = 0; e2 < 4; ++e2) {
        float zn0 = (zv[j * 8 + e2 * 2] - mean) * rinv * zsv[j * 8 + e2 * 2] + zbv[j * 8 + e2 * 2];
        float zn1 = (zv[j * 8 + e2 * 2 + 1] - mean) * rinv * zsv[j * 8 + e2 * 2 + 1] + zbv[j * 8 + e2 * 2 + 1];
        afr.u[e2] = (u32)f2bf(zn0) | ((u32)f2bf(zn1) << 16);
      }
      acc = __builtin_amdgcn_mfma_f32_16x16x32_bf16(afr.b, wf[j].b, acc, 0, 0, 0);
    }

    int kbase = kt * 16 + lgrp * 4;
    float v0 = acc[0] + qadd + 1.0e8f * (xmask[b * 512 + kbase + 0] - 1.0f);
    float v1 = acc[1] + qadd + 1.0e8f * (xmask[b * 512 + kbase + 1] - 1.0f);
    float v2 = acc[2] + qadd + 1.0e8f * (xmask[b * 512 + kbase + 2] - 1.0f);
    float v3 = acc[3] + qadd + 1.0e8f * (xmask[b * 512 + kbase + 3] - 1.0f);
    u16* outp = biasb + (((size_t)(b * 16 + lrow) * 512 + qi) * 512 + kbase);
    *(u32*)outp       = (u32)f2bf(v0) | ((u32)f2bf(v1) << 16);
    *(u32*)(outp + 2) = (u32)f2bf(v2) | ((u32)f2bf(v3) << 16);
  }
}

// ---------------------------------------------------------------------------
// mega0: biasz (1024) ∪ wtrans (3200) ∪ ln_cond_x (1024) — all independent.
// biasz blocks first (longest; streams z while transposes fill spare CUs).
// ---------------------------------------------------------------------------
__global__ __launch_bounds__(256) void mega0(
    const float* __restrict__ z, const float* __restrict__ zs, const float* __restrict__ zbias,
    const float* __restrict__ wb, const float* __restrict__ xmask, u16* __restrict__ biasb,
    const float* __restrict__ gamma_w, const float* __restrict__ beta_w,
    const float* __restrict__ w_cg, const float* __restrict__ w_q,
    const float* __restrict__ w_kv, const float* __restrict__ w_og,
    const float* __restrict__ w_out, const float* __restrict__ w_a,
    const float* __restrict__ w_b2, const float* __restrict__ w_o,
    u16* __restrict__ gbT, u16* __restrict__ cgT, u16* __restrict__ qkvT,
    u16* __restrict__ woT, u16* __restrict__ abT, u16* __restrict__ oT,
    const float* __restrict__ cond, const float* __restrict__ x,
    u16* __restrict__ cnb, u16* __restrict__ cb, float* __restrict__ xstat) {
  __shared__ float Tsh[64][65];
  int id = blockIdx.x;
  if (id < 1024) {
    biasz_body(id, z, zs, zbias, wb, xmask, biasb);
  } else if (id < 4224) {
    wtrans_body(id - 1024, Tsh, gamma_w, beta_w, w_cg, w_q, w_kv, w_og, w_out, w_a, w_b2, w_o,
                gbT, cgT, qkvT, woT, abT, oT);
  } else {
    ln_cond_x_body(id - 4224, cond, x, cnb, cb, xstat);
  }
}

// ---------------------------------------------------------------------------
// Flash attention per (b,h,q-tile-64). q/k/og from fused qkv; V from vT.
// Bias tile staged through LDS; next-tile loads prefetched (T14) so HBM
// latency hides under QK^T+softmax+PV (1 block/CU -> no TLP, ILP only).
// Fused epilogue: gu = (O/l) * sigmoid(og) -> bf16
// ---------------------------------------------------------------------------
__global__ __launch_bounds__(256) void attn(const u16* __restrict__ qkv, const u16* __restrict__ vT,
                                            const u16* __restrict__ biasb, u16* __restrict__ gub) {
  __shared__ u16 Ks[64 * 64];
  __shared__ u16 Vs[64 * 64];
  __shared__ u16 Ps[4][16 * 64];
  __shared__ u16 Bbs[64 * 64];
  const int t = threadIdx.x, wave = t >> 6, lane = t & 63;
  const int lrow = lane & 15, lgrp = lane >> 4;
  const int bh = blockIdx.x >> 3, qt = blockIdx.x & 7;
  const int b = bh >> 4, h = bh & 15;
  const int q0 = qt * 64 + wave * 16;

  Frag qf[2];
#pragma unroll
  for (int ks = 0; ks < 2; ++ks) {
    int tok = b * 512 + q0 + lrow;
    qf[ks].u = *(const u32x4*)(qkv + (size_t)tok * 4096 + h * 64 + ks * 32 + lgrp * 8);
  }
  f32x4 oacc[4] = {};
  float mrun[4], lrun[4];
#pragma unroll
  for (int rg = 0; rg < 4; ++rg) { mrun[rg] = -3.0e38f; lrun[rg] = 0.0f; }

  const int o0 = t * 16, o1 = 4096 + t * 16;
  const int r0 = o0 >> 7, s0 = (o0 >> 4) & 7;
  const int r1 = o1 >> 7, s1 = (o1 >> 4) & 7;
  const int c0 = (s0 ^ (r0 & 7)) << 3;
  const int c1 = (s1 ^ (r1 & 7)) << 3;
  const int br0 = t >> 3, bs0 = t & 7;
  const int br1 = 32 + (t >> 3);
  const u16* bbase = biasb + ((size_t)bh * 512 + qt * 64) * 512;

  const u16* kp0 = qkv + (size_t)(b * 512 + r0) * 4096 + 1024 + h * 64 + c0;
  const u16* kp1 = qkv + (size_t)(b * 512 + r1) * 4096 + 1024 + h * 64 + c1;
  const u16* vp0 = vT + (size_t)(bh * 64 + r0) * 512 + c0;
  const u16* vp1 = vT + (size_t)(bh * 64 + r1) * 512 + c1;
  const u16* bp0 = bbase + (size_t)br0 * 512 + bs0 * 8;
  const u16* bp1 = bbase + (size_t)br1 * 512 + bs0 * 8;

  u32x4 kv0 = *(const u32x4*)(kp0);
  u32x4 kv1 = *(const u32x4*)(kp1);
  u32x4 vv0 = *(const u32x4*)(vp0);
  u32x4 vv1 = *(const u32x4*)(vp1);
  u32x4 bb0 = *(const u32x4*)(bp0);
  u32x4 bb1 = *(const u32x4*)(bp1);

  for (int kt = 0; kt < 8; ++kt) {
    __syncthreads();
    *(u32x4*)((char*)Ks + o0) = kv0;
    *(u32x4*)((char*)Ks + o1) = kv1;
    *(u32x4*)((char*)Vs + o0) = vv0;
    *(u32x4*)((char*)Vs + o1) = vv1;
    *(u32x4*)((char*)Bbs + br0 * 128 + ((bs0 ^ (br0 & 7)) << 4)) = bb0;
    *(u32x4*)((char*)Bbs + br1 * 128 + ((bs0 ^ (br1 & 7)) << 4)) = bb1;
    __syncthreads();

    {
      int k1g = ((kt + 1) & 7) * 64;
      kv0 = *(const u32x4*)(kp0 + (size_t)k1g * 4096);
      kv1 = *(const u32x4*)(kp1 + (size_t)k1g * 4096);
      vv0 = *(const u32x4*)(vp0 + k1g);
      vv1 = *(const u32x4*)(vp1 + k1g);
      bb0 = *(const u32x4*)(bp0 + k1g);
      bb1 = *(const u32x4*)(bp1 + k1g);
    }

    f32x4 sf[4] = {};
#pragma unroll
    for (int ks = 0; ks < 2; ++ks) {
#pragma unroll
      for (int ni = 0; ni < 4; ++ni) {
        int row = ni * 16 + lrow;
        int slot = (ks * 4 + lgrp) ^ (row & 7);
        Frag kf;
        kf.u = *(const u32x4*)((const char*)Ks + row * 128 + (slot << 4));
        sf[ni] = __builtin_amdgcn_mfma_f32_16x16x32_bf16(qf[ks].b, kf.b, sf[ni], 0, 0, 0);
      }
    }

    float sv[4][4];
#pragma unroll
    for (int ni = 0; ni < 4; ++ni) {
#pragma unroll
      for (int rg = 0; rg < 4; ++rg) {
        int qlocal = wave * 16 + lgrp * 4 + rg;
        int k = ni * 16 + lrow;
        float bvv = bf2f(*(const u16*)((const char*)Bbs + qlocal * 128 +
                                       (((k >> 3) ^ (qlocal & 7)) << 4) + (k & 7) * 2));
        sv[ni][rg] = sf[ni][rg] * 0.125f + bvv;
      }
    }
    float mnew[4], fac[4];
#pragma unroll
    for (int rg = 0; rg < 4; ++rg) {
      float tm = fmaxf(fmaxf(sv[0][rg], sv[1][rg]), fmaxf(sv[2][rg], sv[3][rg]));
      tm = fmaxf(tm, __shfl_xor(tm, 1));
      tm = fmaxf(tm, __shfl_xor(tm, 2));
      tm = fmaxf(tm, __shfl_xor(tm, 4));
      tm = fmaxf(tm, __shfl_xor(tm, 8));
      mnew[rg] = fmaxf(mrun[rg], tm);
      fac[rg] = __expf(mrun[rg] - mnew[rg]);
      mrun[rg] = mnew[rg];
    }
    float psum[4] = {0.0f, 0.0f, 0.0f, 0.0f};
#pragma unroll
    for (int ni = 0; ni < 4; ++ni)
#pragma unroll
      for (int rg = 0; rg < 4; ++rg) {
        float p = __expf(sv[ni][rg] - mnew[rg]);
        sv[ni][rg] = p;
        psum[rg] += p;
      }
#pragma unroll
    for (int rg = 0; rg < 4; ++rg) {
      float ps = psum[rg];
      ps += __shfl_xor(ps, 1); ps += __shfl_xor(ps, 2);
      ps += __shfl_xor(ps, 4); ps += __shfl_xor(ps, 8);
      lrun[rg] = lrun[rg] * fac[rg] + ps;
#pragma unroll
      for (int nd = 0; nd < 4; ++nd) oacc[nd][rg] *= fac[rg];
    }
#pragma unroll
    for (int ni = 0; ni < 4; ++ni)
#pragma unroll
      for (int rg = 0; rg < 4; ++rg) {
        int prow = lgrp * 4 + rg;
        int col = ni * 16 + lrow;
        int slot = (col >> 3) ^ (prow & 7);
        *(u16*)((char*)Ps[wave] + prow * 128 + (slot << 4) + (col & 7) * 2) = f2bf(sv[ni][rg]);
      }
    Frag paf[2];
#pragma unroll
    for (int ks = 0; ks < 2; ++ks) {
      int slot = (ks * 4 + lgrp) ^ (lrow & 7);
      paf[ks].u = *(const u32x4*)((const char*)Ps[wave] + lrow * 128 + (slot << 4));
    }
#pragma unroll
    for (int ks = 0; ks < 2; ++ks)
#pragma unroll
      for (int nd = 0; nd < 4; ++nd) {
        int row = nd * 16 + lrow;
        int slot = (ks * 4 + lgrp) ^ (row & 7);
        Frag vf;
        vf.u = *(const u32x4*)((const char*)Vs + row * 128 + (slot << 4));
        oacc[nd] = __builtin_amdgcn_mfma_f32_16x16x32_bf16(paf[ks].b, vf.b, oacc[nd], 0, 0, 0);
      }
  }

#pragma unroll
  for (int nd = 0; nd < 4; ++nd) {
#pragma unroll
    for (int rg = 0; rg < 4; ++rg) {
      int tok = b * 512 + q0 + lgrp * 4 + rg;
      int col = h * 64 + nd * 16 + lrow;
      float og = bf2f(qkv[(size_t)tok * 4096 + 3072 + col]);
      float val = oacc[nd][rg] / lrun[rg] * sigmoidf_(og);
      gub[(size_t)tok * 1024 + col] = f2bf(val);
    }
  }
}

// ---------------------------------------------------------------------------
// xl = LN(x1)*ffn_scale + ffn_bias (bf16)
// ---------------------------------------------------------------------------
__global__ __launch_bounds__(256) void ln_affine(const float* __restrict__ x1, const float* __restrict__ fs,
                                                 const float* __restrict__ fb, u16* __restrict__ xlb) {
  const int row = blockIdx.x;
  const int t = threadIdx.x;
  __shared__ float sb[8];
  f32x4 v = *(const f32x4*)(x1 + (size_t)row * 1024 + t * 4);
  float s = v.x + v.y + v.z + v.w;
  float q = v.x * v.x + v.y * v.y + v.z * v.z + v.w * v.w;
  block_reduce2_256(s, q, sb, t);
  float mean = s * (1.0f / 1024.0f);
  float var = q * (1.0f / 1024.0f) - mean * mean;
  float rinv = rsqrtf(var + 1e-5f);
  f32x4 fsv = *(const f32x4*)(fs + t * 4);
  f32x4 fbv = *(const f32x4*)(fb + t * 4);
  u16x4 o;
  o.x = f2bf((v.x - mean) * rinv * fsv.x + fbv.x);
  o.y = f2bf((v.y - mean) * rinv * fsv.y + fbv.y);
  o.z = f2bf((v.z - mean) * rinv * fsv.z + fbv.z);
  o.w = f2bf((v.w - mean) * rinv * fsv.w + fbv.w);
  *(u16x4*)(xlb + (size_t)row * 1024 + t * 4) = o;
}

// ---------------------------------------------------------------------------
extern "C" void kernel_launch(void* const* d_in, const int* in_sizes, int n_in,
                              void* d_out, int out_size, void* d_ws, size_t ws_size,
                              hipStream_t stream) {
  (void)in_sizes; (void)n_in; (void)out_size; (void)ws_size;
  const float* x        = (const float*)d_in[0];
  const float* cond     = (const float*)d_in[1];
  const float* z        = (const float*)d_in[2];
  const float* xmask    = (const float*)d_in[3];
  const float* gamma_w  = (const float*)d_in[4];
  const float* gamma_b  = (const float*)d_in[5];
  const float* beta_w   = (const float*)d_in[6];
  const float* z_scale  = (const float*)d_in[7];
  const float* z_bias   = (const float*)d_in[8];
  const float* w_q      = (const float*)d_in[9];
  const float* w_kv     = (const float*)d_in[10];
  const float* w_b      = (const float*)d_in[11];
  const float* w_og     = (const float*)d_in[12];
  const float* w_out    = (const float*)d_in[13];
  const float* w_cg     = (const float*)d_in[14];
  const float* b_cg     = (const float*)d_in[15];
  const float* ffn_scale= (const float*)d_in[16];
  const float* ffn_bias = (const float*)d_in[17];
  const float* w_a      = (const float*)d_in[18];
  const float* w_b2     = (const float*)d_in[19];
  const float* w_o      = (const float*)d_in[20];
  float* out = (float*)d_out;

  char* ws = (char*)d_ws;
  size_t off = 0;
  auto alloc = [&](size_t bytes) -> void* {
    void* p = ws + off;
    off += (bytes + 255) & ~(size_t)255;
    return p;
  };
  u16* cnb     = (u16*)alloc(1024 * 512 * 2);
  u16* cb      = (u16*)alloc(1024 * 512 * 2);
  float* xstat = (float*)alloc(1024 * 2 * 4);
  float* cglin = (float*)alloc((size_t)1024 * 1024 * 4);
  u16* xbf     = (u16*)alloc((size_t)1024 * 1024 * 2);
  u16* qkv     = (u16*)alloc((size_t)1024 * 4096 * 2);
  u16* vT      = (u16*)alloc((size_t)2048 * 512 * 2);
  u16* biasb   = (u16*)alloc((size_t)32 * 512 * 512 * 2);
  u16* gub     = (u16*)alloc((size_t)1024 * 1024 * 2);
  float* x1    = (float*)alloc((size_t)1024 * 1024 * 4);
  u16* xlb     = (u16*)alloc((size_t)1024 * 1024 * 2);
  u16* hb      = (u16*)alloc((size_t)1024 * 2048 * 2);
  u16* gbT     = (u16*)alloc((size_t)2048 * 512 * 2);
  u16* cgT     = (u16*)alloc((size_t)1024 * 512 * 2);
  u16* qkvT    = (u16*)alloc((size_t)4096 * 1024 * 2);
  u16* woT     = (u16*)alloc((size_t)1024 * 1024 * 2);
  u16* abT     = (u16*)alloc((size_t)4096 * 1024 * 2);
  u16* oT      = (u16*)alloc((size_t)1024 * 2048 * 2);

  // 1) biasz ∪ weight transposes ∪ (x stats + cond LN), one launch
  mega0<<<5248, 256, 0, stream>>>(
      z, z_scale, z_bias, w_b, xmask, biasb,
      gamma_w, beta_w, w_cg, w_q, w_kv, w_og, w_out, w_a, w_b2, w_o,
      gbT, cgT, qkvT, woT, abT, oT,
      cond, x, cnb, cb, xstat);

  // 2) AdaLN gemm (256) ∪ cond-gate gemm (512, NI2) -> 768 blocks, 3/CU
  gemm_adaln_cg<<<768, 256, 0, stream>>>(cnb, gbT, gamma_b, x, xstat, xbf,
                                         cb, cgT, b_cg, cglin);

  // 3) fused q|k|v|og projection; V columns transposed to vT (EPI6)
  //    MI2/NI4 -> 512 blocks = 2 blocks/CU
  gemm_t<6, 2, 4><<<dim3(16, 32), 256, 0, stream>>>(xbf, qkvT, (const float*)vT, nullptr, nullptr,
                                                    qkv, 1024, 4096, 1024);

  // 4) attention (bias staged via LDS, tile prefetch)
  attn<<<256, 256, 0, stream>>>(qkv, vT, biasb, gub);

  // 5) out-proj fused with residual: x1 = x + (gub@w_out) * sigmoid(cglin)
  //    MI1/NI2 -> 512 blocks = 2 blocks/CU
  gemm_t<2, 1, 2><<<dim3(32, 16), 256, 0, stream>>>(gub, woT, nullptr, x, cglin, x1, 1024, 1024, 1024);

  // 6) xl = LN(x1)*ffn_scale + ffn_bias
  ln_affine<<<1024, 256, 0, stream>>>(x1, ffn_scale, ffn_bias, xlb);

  // 7) fused a|b2 FFN projection with SwiGLU epilogue (interleaved abT)
  //    MI2/NI4 -> 512 blocks = 2 blocks/CU
  gemm_t<4, 2, 4><<<dim3(16, 32), 256, 0, stream>>>(xlb, abT, nullptr, nullptr, nullptr, hb, 1024, 4096, 1024);

  // 8) FFN out fused with masked residual: out = x1 + (hb@w_o) * xmask[row]
  //    MI1/NI2 -> 512 blocks = 2 blocks/CU
  gemm_t<3, 1, 2><<<dim3(32, 16), 256, 0, stream>>>(hb, oT, nullptr, x1, xmask, out, 1024, 1024, 2048);
}